// Round 3
// baseline (428.434 us; speedup 1.0000x reference)
//
#include <hip/hip_runtime.h>
#include <hip/hip_bf16.h>
#include <math.h>

typedef short short8 __attribute__((ext_vector_type(8)));
typedef short sh4 __attribute__((ext_vector_type(4)));
typedef float f32x4 __attribute__((ext_vector_type(4)));
typedef unsigned int u32;
typedef unsigned int u32x4 __attribute__((ext_vector_type(4)));
typedef unsigned int u32x2 __attribute__((ext_vector_type(2)));

#define QBF 127.0f
#define EPSF 1e-5f

#define BB 8
#define SS 32768
#define FF 128
#define K1 256
#define NROWS (BB * SS)      /* 262144 */
#define BM 64
#define NBLK (NROWS / BM)    /* 4096 blocks, 4 waves each, 16 rows/wave */
#define TPB (SS / BM)        /* 512 tiles per batch */

// pack two f32 (whose values are small exact integers) into bf16x2 (u32)
static __device__ __forceinline__ u32 packbf2(float a, float b) {
    u32 ua = __builtin_bit_cast(u32, a);
    u32 ub = __builtin_bit_cast(u32, b);
    return (ua >> 16) | (ub & 0xFFFF0000u);
}
static __device__ __forceinline__ float qf(float v, float s) {
    return fminf(fmaxf(rintf(v * s), -128.f), 127.f);
}

// 16x16x16 bf16 MFMA: builtin if available, else raw ISA (cdna4_isa.md §10)
static __device__ __forceinline__ f32x4 mfma16(sh4 a, sh4 b, f32x4 c) {
#if __has_builtin(__builtin_amdgcn_mfma_f32_16x16x16bf16_1k)
    return __builtin_amdgcn_mfma_f32_16x16x16bf16_1k(a, b, c, 0, 0, 0);
#elif __has_builtin(__builtin_amdgcn_mfma_f32_16x16x16_bf16)
    return __builtin_amdgcn_mfma_f32_16x16x16_bf16(a, b, c, 0, 0, 0);
#else
    f32x4 d;
    asm volatile("v_mfma_f32_16x16x16_bf16 %0, %1, %2, %3\n\ts_nop 7\n\ts_nop 7"
                 : "=v"(d) : "v"(a), "v"(b), "v"(c));
    return d;
#endif
}

// ---------------- kernel 1: weight absmean (f64 accum) ----------------
__global__ void wstats_kernel(const float* __restrict__ W1,
                              const float* __restrict__ W2,
                              float* __restrict__ hdr) {
    __shared__ double red[1024];
    int t = threadIdx.x;
    double s = 0.0;
    #pragma unroll
    for (int i = 0; i < 8; ++i) {
        float4 v = *(const float4*)(W1 + (i * 1024 + t) * 4);
        s += (double)fabsf(v.x) + (double)fabsf(v.y)
           + (double)fabsf(v.z) + (double)fabsf(v.w);
    }
    red[t] = s; __syncthreads();
    for (int o = 512; o > 0; o >>= 1) { if (t < o) red[t] += red[t + o]; __syncthreads(); }
    if (t == 0) hdr[0] = 1.0f / fmaxf((float)(red[0] * (1.0 / 32768.0)), EPSF);
    __syncthreads();
    s = 0.0;
    #pragma unroll
    for (int i = 0; i < 4; ++i) {
        float4 v = *(const float4*)(W2 + (i * 1024 + t) * 4);
        s += (double)fabsf(v.x) + (double)fabsf(v.y)
           + (double)fabsf(v.z) + (double)fabsf(v.w);
    }
    red[t] = s; __syncthreads();
    for (int o = 512; o > 0; o >>= 1) { if (t < o) red[t] += red[t + o]; __syncthreads(); }
    if (t == 0) hdr[1] = 1.0f / fmaxf((float)(red[0] * (1.0 / 16384.0)), EPSF);
}

// ---------------- kernel 2: ternary weight quant -> bf16 ----------------
__global__ void wquant_kernel(const float* __restrict__ W1,
                              const float* __restrict__ W2,
                              const float* __restrict__ hdr,
                              unsigned short* __restrict__ wq1,
                              unsigned short* __restrict__ wq2) {
    int i = blockIdx.x * 256 + threadIdx.x;
    float ws1 = hdr[0], ws2 = hdr[1];
    if (i < 32768) {
        float q = fminf(fmaxf(rintf(W1[i] * ws1), -1.f), 1.f);
        wq1[i] = (unsigned short)(__builtin_bit_cast(u32, q) >> 16);
    }
    if (i < 16384) {
        float q = fminf(fmaxf(rintf(W2[i] * ws2), -1.f), 1.f);
        wq2[i] = (unsigned short)(__builtin_bit_cast(u32, q) >> 16);
    }
}

// ---------------- kernel 3: fused main pass (barrier-free per wave) --------
// Each wave owns 16 rows end-to-end in registers. Swapped layer-1
// (D1 = W1q * Xq^T) makes every per-row stat lane-local; layer-2 uses
// 16x16x16 MFMA whose A/B k-layout (k = 4*lg + e) equals layer-1's C-layout,
// so hq feeds from registers with zero data movement. One tiny barrier at
// the end for block column sums (2 KB LDS).
__global__ __launch_bounds__(256, 4) void fused_kernel(
    const float* __restrict__ evid, const float* __restrict__ prior,
    const float* __restrict__ bias1, const float* __restrict__ bias2,
    const unsigned short* __restrict__ wq1, const unsigned short* __restrict__ wq2,
    const float* __restrict__ hdr, float* __restrict__ out,
    float* __restrict__ partials)
{
    __shared__ float colsum[4][FF];

    const int tid = threadIdx.x;
    const int w = tid >> 6, l = tid & 63;
    const int lr = l & 15, lg = l >> 4;
    const int tile = blockIdx.x * 4 + w;
    const int grow = tile * 16 + lr;
    const float ws1 = hdr[0], ws2 = hdr[1];

    const float* prow = prior + (size_t)grow * FF;
    const float* erow = evid + (size_t)grow * FF;

    // ---- Phase A: load x in fragment layout, row absmax, quantize ----
    // lane (lr,lg) holds x[row=grow][k = kb*32 + lg*8 + 0..7], kb=0..7
    float4 xr[16];
    #pragma unroll
    for (int kb = 0; kb < 8; ++kb) {
        const float* src = (kb < 4) ? (prow + kb * 32) : (erow + (kb - 4) * 32);
        xr[2 * kb]     = *(const float4*)(src + lg * 8);
        xr[2 * kb + 1] = *(const float4*)(src + lg * 8 + 4);
    }
    float m = EPSF;
    #pragma unroll
    for (int i = 0; i < 16; ++i) {
        float4 v = xr[i];
        m = fmaxf(m, fmaxf(fmaxf(fabsf(v.x), fabsf(v.y)),
                           fmaxf(fabsf(v.z), fabsf(v.w))));
    }
    m = fmaxf(m, __shfl_xor(m, 16, 64));
    m = fmaxf(m, __shfl_xor(m, 32, 64));     // 4 lanes of this row now agree
    const float s1 = QBF / m;

    u32x4 xq[8];
    #pragma unroll
    for (int kb = 0; kb < 8; ++kb) {
        float4 v0 = xr[2 * kb], v1 = xr[2 * kb + 1];
        u32x4 t;
        t.x = packbf2(qf(v0.x, s1), qf(v0.y, s1));
        t.y = packbf2(qf(v0.z, s1), qf(v0.w, s1));
        t.z = packbf2(qf(v1.x, s1), qf(v1.y, s1));
        t.w = packbf2(qf(v1.z, s1), qf(v1.w, s1));
        xq[kb] = t;
    }

    // ---- Layer 1: D1[c][r] = sum_k W1q[c][k] * xq[r][k]  (8 col-tiles) ----
    f32x4 acc1[8] = {};
    const unsigned short* wp1 = wq1 + lr * K1 + lg * 8;
    #pragma unroll
    for (int kb = 0; kb < 8; ++kb) {
        short8 b = __builtin_bit_cast(short8, xq[kb]);
        #pragma unroll
        for (int ct = 0; ct < 8; ++ct) {
            short8 a = *(const short8*)(wp1 + ct * 16 * K1 + kb * 32);
            acc1[ct] = __builtin_amdgcn_mfma_f32_16x16x32_bf16(a, b, acc1[ct], 0, 0, 0);
        }
    }

    // ---- Epilogue 1: lane-local h row, relu, row-max, requant ----
    const float rinv1 = 1.0f / (s1 * ws1);
    float h[8][4];
    float hm = 0.f;
    #pragma unroll
    for (int ct = 0; ct < 8; ++ct) {
        float4 b4 = *(const float4*)(bias1 + ct * 16 + lg * 4);
        float bb[4] = {b4.x, b4.y, b4.z, b4.w};
        #pragma unroll
        for (int j = 0; j < 4; ++j) {
            float y = acc1[ct][j] * rinv1 + bb[j];
            y = fmaxf(y, 0.f);
            h[ct][j] = y;
            hm = fmaxf(hm, y);
        }
    }
    hm = fmaxf(hm, __shfl_xor(hm, 16, 64));
    hm = fmaxf(hm, __shfl_xor(hm, 32, 64));
    const float s2 = QBF / fmaxf(hm, EPSF);
    const float rinv2 = 1.0f / (s2 * ws2);

    u32x2 hq[8];
    #pragma unroll
    for (int ct = 0; ct < 8; ++ct) {
        u32x2 t;
        t.x = packbf2(qf(h[ct][0], s2), qf(h[ct][1], s2));
        t.y = packbf2(qf(h[ct][2], s2), qf(h[ct][3], s2));
        hq[ct] = t;   // h^T[k = 16*ct + 4*lg + j][row lr] == B-frag of 16x16x16
    }

    // ---- Layer 2: D2[c2][r] = sum_k W2q[c2][k] * hq[r][k] ----
    f32x4 acc2[8] = {};
    const unsigned short* wp2 = wq2 + lr * FF + lg * 4;
    #pragma unroll
    for (int kb = 0; kb < 8; ++kb) {
        sh4 b2 = __builtin_bit_cast(sh4, hq[kb]);
        #pragma unroll
        for (int ct = 0; ct < 8; ++ct) {
            sh4 a2 = *(const sh4*)(wp2 + ct * 16 * FF + kb * 16);
            acc2[ct] = mfma16(a2, b2, acc2[ct]);
        }
    }

    // ---- Epilogue 2: sigmoid, * prior, float4 store, column sums ----
    float* orow = out + (size_t)grow * FF;
    float cs[8][4];
    #pragma unroll
    for (int ct = 0; ct < 8; ++ct) {
        float4 b4 = *(const float4*)(bias2 + ct * 16 + lg * 4);
        float4 pv = *(const float4*)(prow + ct * 16 + lg * 4);
        float bb[4] = {b4.x, b4.y, b4.z, b4.w};
        float pp[4] = {pv.x, pv.y, pv.z, pv.w};
        float4 un;
        float uu[4];
        #pragma unroll
        for (int j = 0; j < 4; ++j) {
            float y = acc2[ct][j] * rinv2 + bb[j];
            float lik = 1.0f / (1.0f + __expf(-y));
            uu[j] = pp[j] * lik;
            cs[ct][j] = uu[j];
        }
        un.x = uu[0]; un.y = uu[1]; un.z = uu[2]; un.w = uu[3];
        *(float4*)(orow + ct * 16 + lg * 4) = un;
    }
    // reduce over the wave's 16 rows (lr lanes)
    #pragma unroll
    for (int msk = 1; msk < 16; msk <<= 1) {
        #pragma unroll
        for (int ct = 0; ct < 8; ++ct) {
            #pragma unroll
            for (int j = 0; j < 4; ++j)
                cs[ct][j] += __shfl_xor(cs[ct][j], msk, 64);
        }
    }
    if (lr < 4) {   // lane lr supplies element j == lr (static indices only)
        #pragma unroll
        for (int ct = 0; ct < 8; ++ct) {
            float v = (lr == 0) ? cs[ct][0] : (lr == 1) ? cs[ct][1]
                    : (lr == 2) ? cs[ct][2] : cs[ct][3];
            colsum[w][ct * 16 + lg * 4 + lr] = v;
        }
    }
    __syncthreads();
    if (tid < FF) {
        float p = colsum[0][tid] + colsum[1][tid] + colsum[2][tid] + colsum[3][tid];
        partials[(size_t)blockIdx.x * FF + tid] = p;
    }
}

// ---------------- kernel 4: deterministic normalizer reduction ----------------
__global__ void norm_kernel(const float* __restrict__ partials, float* __restrict__ norm) {
    __shared__ float red[4][128];
    int b = blockIdx.x;                                // 8 blocks
    int f = threadIdx.x & 127, tg = threadIdx.x >> 7;  // 512 threads
    float s = 0.f;
    for (int t = tg * 128; t < tg * 128 + 128; ++t)
        s += partials[((size_t)b * TPB + t) * FF + f];
    red[tg][f] = s; __syncthreads();
    if (tg == 0) {
        float tot = red[0][f] + red[1][f] + red[2][f] + red[3][f];
        norm[b * FF + f] = fmaxf(tot, 1e-10f);
    }
}

// ---------------- kernel 5: out /= norm ----------------
__global__ void div_kernel(float* __restrict__ out, const float* __restrict__ norm) {
    size_t i4 = (size_t)blockIdx.x * blockDim.x + threadIdx.x;
    const size_t total4 = (size_t)NROWS * FF / 4;
    for (; i4 < total4; i4 += (size_t)gridDim.x * blockDim.x) {
        size_t i = i4 * 4;
        float4 v = *(float4*)(out + i);
        int b = (int)(i >> 22);                  // S*F = 2^22
        int f = (int)(i & 127);
        float4 nv = *(const float4*)(norm + b * FF + f);
        v.x /= nv.x; v.y /= nv.y; v.z /= nv.z; v.w /= nv.w;
        *(float4*)(out + i) = v;
    }
}

extern "C" void kernel_launch(void* const* d_in, const int* in_sizes, int n_in,
                              void* d_out, int out_size, void* d_ws, size_t ws_size,
                              hipStream_t stream) {
    const float* evid  = (const float*)d_in[0];
    const float* prior = (const float*)d_in[1];
    const float* W1    = (const float*)d_in[2];
    const float* b1    = (const float*)d_in[3];
    const float* W2    = (const float*)d_in[4];
    const float* b2    = (const float*)d_in[5];
    float* out = (float*)d_out;

    char* ws = (char*)d_ws;
    float* hdr           = (float*)ws;                                  // 64 B
    unsigned short* wq1  = (unsigned short*)(ws + 256);                 // 64 KB
    unsigned short* wq2  = (unsigned short*)(ws + 256 + 65536);         // 32 KB
    float* partials      = (float*)(ws + 256 + 65536 + 32768);          // 2 MB
    float* norm          = (float*)(ws + 256 + 65536 + 32768 + 2097152);// 4 KB

    wstats_kernel<<<1, 1024, 0, stream>>>(W1, W2, hdr);
    wquant_kernel<<<128, 256, 0, stream>>>(W1, W2, hdr, wq1, wq2);
    fused_kernel<<<NBLK, 256, 0, stream>>>(evid, prior, b1, b2, wq1, wq2, hdr, out, partials);
    norm_kernel<<<8, 512, 0, stream>>>(partials, norm);
    div_kernel<<<2048, 256, 0, stream>>>(out, norm);
}

// Round 4
// 299.528 us; speedup vs baseline: 1.4304x; 1.4304x over previous
//
#include <hip/hip_runtime.h>
#include <hip/hip_bf16.h>
#include <math.h>

typedef short short8 __attribute__((ext_vector_type(8)));
typedef short sh4 __attribute__((ext_vector_type(4)));
typedef float f32x4 __attribute__((ext_vector_type(4)));
typedef unsigned int u32;
typedef unsigned int u32x2 __attribute__((ext_vector_type(2)));
typedef unsigned short us8 __attribute__((ext_vector_type(8)));
typedef unsigned short us4v __attribute__((ext_vector_type(4)));

#define QBF 127.0f
#define EPSF 1e-5f

#define BB 8
#define SS 32768
#define FF 128
#define K1 256
#define NROWS (BB * SS)      /* 262144 */
#define NBLK (NROWS / 64)    /* 4096 blocks, 4 waves, 16 rows/wave */
#define TPB (SS / 64)        /* 512 tiles per batch */

static __device__ __forceinline__ u32 packbf2(float a, float b) {
    // exact: values are small integers, low 16 mantissa bits are zero
    return (__builtin_bit_cast(u32, a) >> 16) | (__builtin_bit_cast(u32, b) & 0xFFFF0000u);
}
static __device__ __forceinline__ float qf(float v, float s) {
    return fminf(fmaxf(rintf(v * s), -128.f), 127.f);
}
static __device__ __forceinline__ float bcast_lane(float v, int lane) {
    return __builtin_bit_cast(float, __builtin_amdgcn_readlane(__builtin_bit_cast(int, v), lane));
}

// 16x16x16 bf16 MFMA (verified correct in R3)
static __device__ __forceinline__ f32x4 mfma16(sh4 a, sh4 b, f32x4 c) {
#if __has_builtin(__builtin_amdgcn_mfma_f32_16x16x16bf16_1k)
    return __builtin_amdgcn_mfma_f32_16x16x16bf16_1k(a, b, c, 0, 0, 0);
#elif __has_builtin(__builtin_amdgcn_mfma_f32_16x16x16_bf16)
    return __builtin_amdgcn_mfma_f32_16x16x16_bf16(a, b, c, 0, 0, 0);
#else
    f32x4 d;
    asm volatile("v_mfma_f32_16x16x16_bf16 %0, %1, %2, %3\n\ts_nop 7\n\ts_nop 7"
                 : "=v"(d) : "v"(a), "v"(b), "v"(c));
    return d;
#endif
}

// ---------------- kernel 1: weight absmean (f64 accum) ----------------
__global__ void wstats_kernel(const float* __restrict__ W1,
                              const float* __restrict__ W2,
                              float* __restrict__ hdr) {
    __shared__ double red[1024];
    int t = threadIdx.x;
    double s = 0.0;
    #pragma unroll
    for (int i = 0; i < 8; ++i) {
        float4 v = *(const float4*)(W1 + (i * 1024 + t) * 4);
        s += (double)fabsf(v.x) + (double)fabsf(v.y)
           + (double)fabsf(v.z) + (double)fabsf(v.w);
    }
    red[t] = s; __syncthreads();
    for (int o = 512; o > 0; o >>= 1) { if (t < o) red[t] += red[t + o]; __syncthreads(); }
    if (t == 0) hdr[0] = 1.0f / fmaxf((float)(red[0] * (1.0 / 32768.0)), EPSF);
    __syncthreads();
    s = 0.0;
    #pragma unroll
    for (int i = 0; i < 4; ++i) {
        float4 v = *(const float4*)(W2 + (i * 1024 + t) * 4);
        s += (double)fabsf(v.x) + (double)fabsf(v.y)
           + (double)fabsf(v.z) + (double)fabsf(v.w);
    }
    red[t] = s; __syncthreads();
    for (int o = 512; o > 0; o >>= 1) { if (t < o) red[t] += red[t + o]; __syncthreads(); }
    if (t == 0) hdr[1] = 1.0f / fmaxf((float)(red[0] * (1.0 / 16384.0)), EPSF);
}

// ---------------- kernel 2: quantize weights into FRAGMENT-ORDERED layout ----
// wq1: granule (ct,kb) of 512 elems; lane l = lg*16+lr holds elems [l*8..l*8+7]
//      = W1[ct*16+lr][kb*32+lg*8+e]  -> coalesced 1KB short8 loads in fused.
// wq2: granule (ct,kb) of 256 elems; lane l holds [l*4..l*4+3]
//      = W2[ct*16+lr][kb*16+lg*4+e]  -> coalesced 512B sh4 loads.
__global__ void wquant_kernel(const float* __restrict__ W1,
                              const float* __restrict__ W2,
                              const float* __restrict__ hdr,
                              unsigned short* __restrict__ wq1,
                              unsigned short* __restrict__ wq2) {
    int gid = blockIdx.x * 256 + threadIdx.x;   // 8192 threads
    float ws1 = hdr[0], ws2 = hdr[1];
    if (gid < 4096) {
        int g = gid;
        int o = g >> 5, k8 = g & 31;             // o: out-ch, k8: 8-elem k-granule
        int ct = o >> 4, lr = o & 15, kb = k8 >> 2, lg = k8 & 3;
        const float* s = W1 + o * 256 + k8 * 8;
        us8 q;
        #pragma unroll
        for (int e = 0; e < 8; ++e) {
            float v = fminf(fmaxf(rintf(s[e] * ws1), -1.f), 1.f);
            q[e] = (unsigned short)(__builtin_bit_cast(u32, v) >> 16);
        }
        *(us8*)(wq1 + (ct * 8 + kb) * 512 + lg * 128 + lr * 8) = q;
    } else {
        int g = gid - 4096;
        int o = g >> 5, k4 = g & 31;             // k4: 4-elem k-granule
        int ct = o >> 4, lr = o & 15, kb = k4 >> 2, lg = k4 & 3;
        const float* s = W2 + o * 128 + k4 * 4;
        us4v q;
        #pragma unroll
        for (int e = 0; e < 4; ++e) {
            float v = fminf(fmaxf(rintf(s[e] * ws2), -1.f), 1.f);
            q[e] = (unsigned short)(__builtin_bit_cast(u32, v) >> 16);
        }
        *(us4v*)(wq2 + (ct * 8 + kb) * 256 + lg * 64 + lr * 4) = q;
    }
}

// ---------------- kernel 3: fused main pass ----------------
// Wave-independent (16 rows/wave, own 8KB LDS region). Every global access is
// wave-coalesced; LDS does all layout conversion (XOR-swizzled, ~conflict-free).
// Middle (requant h, layer-2) stays register-resident per R3.
__global__ __launch_bounds__(256, 3) void fused_kernel(
    const float* __restrict__ evid, const float* __restrict__ prior,
    const float* __restrict__ bias1, const float* __restrict__ bias2,
    const unsigned short* __restrict__ wq1, const unsigned short* __restrict__ wq2,
    const float* __restrict__ hdr, float* __restrict__ out,
    float* __restrict__ partials)
{
    __shared__ float ldsf[8704];                 // 4*8KB wave regions + 2KB colsum
    float* colsum = ldsf + 8192;

    const int tid = threadIdx.x;
    const int w = tid >> 6, l = tid & 63;
    const int lr = l & 15, lg = l >> 4;
    const int lc = l & 31, half = l >> 5;        // col-group / prior-vs-evid half
    const int R0 = (blockIdx.x * 4 + w) * 16;    // wave's global row base
    char* wbase = (char*)(ldsf) + w * 8192;

    const float ws1 = hdr[0], ws2 = hdr[1];

    // ---- Phase A: coalesced loads (1KB/instr), LDS-transpose row-max ----
    const float* src = half ? evid : prior;
    float4 xr[16];
    #pragma unroll
    for (int r = 0; r < 16; ++r)
        xr[r] = *(const float4*)(src + (size_t)(R0 + r) * FF + lc * 4);

    float* maxtr = (float*)wbase;                // [16][68] padded (bank-spread)
    #pragma unroll
    for (int r = 0; r < 16; ++r) {
        float4 v = xr[r];
        float m = fmaxf(fmaxf(fabsf(v.x), fabsf(v.y)), fmaxf(fabsf(v.z), fabsf(v.w)));
        maxtr[r * 68 + l] = m;
    }
    asm volatile("s_waitcnt lgkmcnt(0)" ::: "memory");
    __builtin_amdgcn_sched_barrier(0);
    float mm;
    {
        const float* p = maxtr + lr * 68 + lg * 16;   // row lr, quarter lg
        float4 a = *(const float4*)(p);
        float4 b = *(const float4*)(p + 4);
        float4 c = *(const float4*)(p + 8);
        float4 d = *(const float4*)(p + 12);
        float m0 = fmaxf(fmaxf(a.x, a.y), fmaxf(a.z, a.w));
        float m1 = fmaxf(fmaxf(b.x, b.y), fmaxf(b.z, b.w));
        float m2 = fmaxf(fmaxf(c.x, c.y), fmaxf(c.z, c.w));
        float m3 = fmaxf(fmaxf(d.x, d.y), fmaxf(d.z, d.w));
        mm = fmaxf(fmaxf(m0, m1), fmaxf(m2, m3));
    }
    mm = fmaxf(mm, __shfl_xor(mm, 16, 64));
    mm = fmaxf(mm, __shfl_xor(mm, 32, 64));
    const float sA = QBF / fmaxf(mm, EPSF);      // scale for row (l&15), all lanes

    // quantize + write bf16 to XOR-swizzled LDS (row scale via readlane->SGPR)
    char* xbuf = wbase;
    #pragma unroll
    for (int r = 0; r < 16; ++r) {
        float s_r = bcast_lane(sA, r);           // lane r holds row r's scale
        u32x2 p;
        p.x = packbf2(qf(xr[r].x, s_r), qf(xr[r].y, s_r));
        p.y = packbf2(qf(xr[r].z, s_r), qf(xr[r].w, s_r));
        int bo = (r * 512 + lc * 8 + half * 256) ^ ((r & 7) << 4);
        *(u32x2*)(xbuf + bo) = p;
    }
    asm volatile("s_waitcnt lgkmcnt(0)" ::: "memory");
    __builtin_amdgcn_sched_barrier(0);

    // ---- Layer 1: D1 = W1q * Xq^T, weights coalesced from L1 ----
    f32x4 acc1[8] = {};
    #pragma unroll
    for (int kb = 0; kb < 8; ++kb) {
        int bo = (lr * 512 + kb * 64 + lg * 16) ^ ((lr & 7) << 4);
        short8 bfr = *(const short8*)(xbuf + bo);
        const unsigned short* wp = wq1 + kb * 512 + l * 8;
        #pragma unroll
        for (int ct = 0; ct < 8; ++ct) {
            short8 a = *(const short8*)(wp + ct * 4096);
            acc1[ct] = __builtin_amdgcn_mfma_f32_16x16x32_bf16(a, bfr, acc1[ct], 0, 0, 0);
        }
    }

    // ---- Epilogue 1 (register): scale+bias+relu, lane-local requant ----
    const float rinv1 = 1.0f / (sA * ws1);       // sA == scale of row lr
    float h[8][4];
    float hm = 0.f;
    #pragma unroll
    for (int ct = 0; ct < 8; ++ct) {
        float4 b4 = *(const float4*)(bias1 + ct * 16 + lg * 4);
        float bb[4] = {b4.x, b4.y, b4.z, b4.w};
        #pragma unroll
        for (int j = 0; j < 4; ++j) {
            float y = fmaxf(acc1[ct][j] * rinv1 + bb[j], 0.f);
            h[ct][j] = y;
            hm = fmaxf(hm, y);
        }
    }
    hm = fmaxf(hm, __shfl_xor(hm, 16, 64));
    hm = fmaxf(hm, __shfl_xor(hm, 32, 64));
    const float s2 = QBF / fmaxf(hm, EPSF);
    const float rinv2 = 1.0f / (s2 * ws2);

    u32x2 hq[8];
    #pragma unroll
    for (int ct = 0; ct < 8; ++ct) {
        u32x2 t;
        t.x = packbf2(qf(h[ct][0], s2), qf(h[ct][1], s2));
        t.y = packbf2(qf(h[ct][2], s2), qf(h[ct][3], s2));
        hq[ct] = t;                              // B-frag of 16x16x16, k=ct*16+lg*4+e
    }

    // ---- Layer 2: D2 = W2q * Hq^T (weights coalesced 512B sh4 loads) ----
    f32x4 acc2[8] = {};
    #pragma unroll
    for (int kb = 0; kb < 8; ++kb) {
        sh4 b2 = __builtin_bit_cast(sh4, hq[kb]);
        const unsigned short* wp = wq2 + kb * 256 + l * 4;
        #pragma unroll
        for (int ct = 0; ct < 8; ++ct) {
            sh4 a2 = *(const sh4*)(wp + ct * 2048);
            acc2[ct] = mfma16(a2, b2, acc2[ct]);
        }
    }

    // ---- Epilogue 2: sigmoid in fragment layout -> LDS transpose ----
    char* ebuf = wbase;                          // reuse (xbuf reads all done)
    #pragma unroll
    for (int ct = 0; ct < 8; ++ct) {
        float4 b4 = *(const float4*)(bias2 + ct * 16 + lg * 4);
        float bb[4] = {b4.x, b4.y, b4.z, b4.w};
        f32x4 lik;
        #pragma unroll
        for (int j = 0; j < 4; ++j) {
            float y = acc2[ct][j] * rinv2 + bb[j];
            lik[j] = 1.0f / (1.0f + __expf(-y));
        }
        int bo = (lr * 512 + ct * 64 + lg * 16) ^ ((lr & 7) << 4);
        *(f32x4*)(ebuf + bo) = lik;
    }
    asm volatile("s_waitcnt lgkmcnt(0)" ::: "memory");
    __builtin_amdgcn_sched_barrier(0);

    // ---- coalesced finish: *prior (L2/L3-hot), store, column sums ----
    float cs0 = 0.f, cs1 = 0.f, cs2 = 0.f, cs3 = 0.f;
    #pragma unroll
    for (int i = 0; i < 8; ++i) {
        int r = 2 * i + half;
        int bo = (r * 512 + lc * 16) ^ ((r & 7) << 4);
        f32x4 lik = *(const f32x4*)(ebuf + bo);
        float4 pv = *(const float4*)(prior + (size_t)(R0 + r) * FF + lc * 4);
        float4 un;
        un.x = pv.x * lik[0]; un.y = pv.y * lik[1];
        un.z = pv.z * lik[2]; un.w = pv.w * lik[3];
        *(float4*)(out + (size_t)(R0 + r) * FF + lc * 4) = un;
        cs0 += un.x; cs1 += un.y; cs2 += un.z; cs3 += un.w;
    }
    cs0 += __shfl_xor(cs0, 32, 64);              // combine odd/even row halves
    cs1 += __shfl_xor(cs1, 32, 64);
    cs2 += __shfl_xor(cs2, 32, 64);
    cs3 += __shfl_xor(cs3, 32, 64);
    if (l < 32) {
        f32x4 c; c[0] = cs0; c[1] = cs1; c[2] = cs2; c[3] = cs3;
        *(f32x4*)(colsum + w * 128 + l * 4) = c;
    }
    __syncthreads();
    if (tid < FF)
        partials[(size_t)blockIdx.x * FF + tid] =
            colsum[tid] + colsum[128 + tid] + colsum[256 + tid] + colsum[384 + tid];
}

// ---------------- kernel 4: deterministic normalizer reduction ----------------
__global__ void norm_kernel(const float* __restrict__ partials, float* __restrict__ norm) {
    __shared__ float red[4][128];
    int b = blockIdx.x;                                // 8 blocks
    int f = threadIdx.x & 127, tg = threadIdx.x >> 7;  // 512 threads
    float s = 0.f;
    for (int t = tg * 128; t < tg * 128 + 128; ++t)
        s += partials[((size_t)b * TPB + t) * FF + f];
    red[tg][f] = s; __syncthreads();
    if (tg == 0) {
        float tot = red[0][f] + red[1][f] + red[2][f] + red[3][f];
        norm[b * FF + f] = fmaxf(tot, 1e-10f);
    }
}

// ---------------- kernel 5: out /= norm ----------------
__global__ void div_kernel(float* __restrict__ out, const float* __restrict__ norm) {
    size_t i4 = (size_t)blockIdx.x * blockDim.x + threadIdx.x;
    const size_t total4 = (size_t)NROWS * FF / 4;
    for (; i4 < total4; i4 += (size_t)gridDim.x * blockDim.x) {
        size_t i = i4 * 4;
        float4 v = *(float4*)(out + i);
        int b = (int)(i >> 22);                  // S*F = 2^22
        int f = (int)(i & 127);
        float4 nv = *(const float4*)(norm + b * FF + f);
        v.x /= nv.x; v.y /= nv.y; v.z /= nv.z; v.w /= nv.w;
        *(float4*)(out + i) = v;
    }
}

extern "C" void kernel_launch(void* const* d_in, const int* in_sizes, int n_in,
                              void* d_out, int out_size, void* d_ws, size_t ws_size,
                              hipStream_t stream) {
    const float* evid  = (const float*)d_in[0];
    const float* prior = (const float*)d_in[1];
    const float* W1    = (const float*)d_in[2];
    const float* b1    = (const float*)d_in[3];
    const float* W2    = (const float*)d_in[4];
    const float* b2    = (const float*)d_in[5];
    float* out = (float*)d_out;

    char* ws = (char*)d_ws;
    float* hdr           = (float*)ws;                                  // 64 B
    unsigned short* wq1  = (unsigned short*)(ws + 256);                 // 64 KB
    unsigned short* wq2  = (unsigned short*)(ws + 256 + 65536);         // 32 KB
    float* partials      = (float*)(ws + 256 + 65536 + 32768);          // 2 MB
    float* norm          = (float*)(ws + 256 + 65536 + 32768 + 2097152);// 4 KB

    wstats_kernel<<<1, 1024, 0, stream>>>(W1, W2, hdr);
    wquant_kernel<<<32, 256, 0, stream>>>(W1, W2, hdr, wq1, wq2);
    fused_kernel<<<NBLK, 256, 0, stream>>>(evid, prior, b1, b2, wq1, wq2, hdr, out, partials);
    norm_kernel<<<8, 512, 0, stream>>>(partials, norm);
    div_kernel<<<2048, 256, 0, stream>>>(out, norm);
}

// Round 5
// 169.072 us; speedup vs baseline: 2.5340x; 1.7716x over previous
//
#include <hip/hip_runtime.h>
#include <hip/hip_bf16.h>
#include <math.h>

typedef int   i32x4 __attribute__((ext_vector_type(4)));
typedef unsigned int u32;

#define QBF 127.0f
#define EPSF 1e-5f
#define FF 128
#define NROWS (8 * 32768)
#define NBLK 512              /* 2 blocks/CU exactly */
#define TPB 8                 /* 64-row tiles per block */

/* LDS map (bytes) */
#define W1_OFF    0           /* 32768: W1 i8 granules (ct*4+kb)*1024 + lane*16 */
#define W2_OFF    32768       /* 16384: W2 i8 granules (ct*2+kb)*1024 + lane*16 */
#define WBUF_OFF  49152       /* 4 waves x 4352 (16 rows x 272B) */
#define CS_OFF    66560       /* 4 x 128 f32 colsum */
#define LDS_TOTAL 68608

#define LGKM0() asm volatile("s_waitcnt lgkmcnt(0)" ::: "memory")
#define SB()    __builtin_amdgcn_sched_barrier(0)

static __device__ __forceinline__ float bcast_lane(float v, int lane) {
    return __builtin_bit_cast(float, __builtin_amdgcn_readlane(__builtin_bit_cast(int, v), lane));
}
static __device__ __forceinline__ u32 packi8(float a, float b, float c, float d, float s) {
    int i0 = (int)rintf(a * s), i1 = (int)rintf(b * s);
    int i2 = (int)rintf(c * s), i3 = (int)rintf(d * s);
    return (u32)(i0 & 0xFF) | ((u32)(i1 & 0xFF) << 8) |
           ((u32)(i2 & 0xFF) << 16) | ((u32)i3 << 24);
}

// ---------- kernel 1a: partial abs-sums (48 blocks, deterministic) ----------
__global__ void pstats_kernel(const float* __restrict__ W1,
                              const float* __restrict__ W2,
                              double* __restrict__ psum) {
    __shared__ double red[256];
    int b = blockIdx.x, t = threadIdx.x;
    const float4* src = (b < 32) ? (const float4*)(W1 + b * 1024)
                                 : (const float4*)(W2 + (b - 32) * 1024);
    float4 v = src[t];
    red[t] = (double)fabsf(v.x) + (double)fabsf(v.y)
           + (double)fabsf(v.z) + (double)fabsf(v.w);
    __syncthreads();
    for (int o = 128; o > 0; o >>= 1) { if (t < o) red[t] += red[t + o]; __syncthreads(); }
    if (t == 0) psum[b] = red[0];
}

// ---------- kernel 1b: finalize scales ----------
__global__ void sfinal_kernel(const double* __restrict__ psum, float* __restrict__ hdr) {
    __shared__ double red[64];
    int t = threadIdx.x;                         // 64 threads
    red[t] = (t < 32) ? psum[t] : 0.0;
    __syncthreads();
    for (int o = 16; o > 0; o >>= 1) { if (t < o) red[t] += red[t + o]; __syncthreads(); }
    double s1 = red[0];
    __syncthreads();
    red[t] = (t < 16) ? psum[32 + t] : 0.0;
    __syncthreads();
    for (int o = 8; o > 0; o >>= 1) { if (t < o) red[t] += red[t + o]; __syncthreads(); }
    if (t == 0) {
        hdr[0] = 1.0f / fmaxf((float)(s1 * (1.0 / 32768.0)), EPSF);
        hdr[1] = 1.0f / fmaxf((float)(red[0] * (1.0 / 16384.0)), EPSF);
    }
}

// ---------- kernel 2: ternary weights -> i8, MFMA-granule layout ----------
// granule g of 1024B: lane l holds 16 bytes = W[ct*16+(l&15)][kb*64+(l>>4)*16 ..+16)
__global__ void wquant_kernel(const float* __restrict__ W1,
                              const float* __restrict__ W2,
                              const float* __restrict__ hdr,
                              char* __restrict__ wq) {
    int g = blockIdx.x * 256 + threadIdx.x;      // 3072 threads
    float ws1 = hdr[0], ws2 = hdr[1];
    const float* src; float wsx; char* dst;
    if (g < 2048) {
        int gi = g >> 6, l = g & 63;
        int ct = gi >> 2, kb = gi & 3;
        src = W1 + (ct * 16 + (l & 15)) * 256 + kb * 64 + (l >> 4) * 16;
        wsx = ws1;
        dst = wq + gi * 1024 + l * 16;
    } else {
        int g2 = g - 2048;
        int gi = g2 >> 6, l = g2 & 63;
        int ct = gi >> 1, kb = gi & 1;
        src = W2 + (ct * 16 + (l & 15)) * 128 + kb * 64 + (l >> 4) * 16;
        wsx = ws2;
        dst = wq + 32768 + gi * 1024 + l * 16;
    }
    u32 o[4];
    #pragma unroll
    for (int q = 0; q < 4; ++q) {
        float4 v = *(const float4*)(src + q * 4);
        float q0 = fminf(fmaxf(rintf(v.x * wsx), -1.f), 1.f);
        float q1 = fminf(fmaxf(rintf(v.y * wsx), -1.f), 1.f);
        float q2 = fminf(fmaxf(rintf(v.z * wsx), -1.f), 1.f);
        float q3 = fminf(fmaxf(rintf(v.w * wsx), -1.f), 1.f);
        o[q] = packi8(q0, q1, q2, q3, 1.0f);
    }
    *(uint4*)dst = make_uint4(o[0], o[1], o[2], o[3]);
}

// ---------- kernel 3: fused main pass ----------
// 512 blocks x 4 waves; weights staged to LDS once/block, reused over 8 tiles.
// Per wave: 16 rows/tile, all-i8 MFMA (exact), register-resident middle.
__global__ __launch_bounds__(256, 2) void fused_kernel(
    const float* __restrict__ evid, const float* __restrict__ prior,
    const float* __restrict__ bias1, const float* __restrict__ bias2,
    const char* __restrict__ wq, const float* __restrict__ hdr,
    float* __restrict__ out, float* __restrict__ partials)
{
    __shared__ __align__(16) char smem[LDS_TOTAL];
    const int tid = threadIdx.x;
    const int w = tid >> 6, l = tid & 63;
    const int lr = l & 15, lg = l >> 4;
    const int lc = l & 31, half = l >> 5;
    char* wbuf = smem + WBUF_OFF + w * 4352;
    float* colsum = (float*)(smem + CS_OFF);
    const float ws1 = hdr[0], ws2 = hdr[1];

    // stage 48KB of i8 weights (linear copy, granule layout preserved)
    {
        const uint4* g = (const uint4*)wq;
        #pragma unroll
        for (int i = 0; i < 12; ++i) {
            uint4 v = g[i * 256 + tid];
            *(uint4*)(smem + (size_t)(i * 256 + tid) * 16) = v;
        }
    }
    // first tile x loads (overlap staging latency)
    float4 xr[16];
    {
        const float* srcp = half ? evid : prior;
        int R0 = blockIdx.x * 512 + w * 16;
        #pragma unroll
        for (int r = 0; r < 16; ++r)
            xr[r] = *(const float4*)(srcp + (size_t)(R0 + r) * FF + lc * 4);
    }
    __syncthreads();

    float csum[8][4];
    #pragma unroll
    for (int ct = 0; ct < 8; ++ct)
        #pragma unroll
        for (int j = 0; j < 4; ++j) csum[ct][j] = 0.f;

    for (int t = 0; t < TPB; ++t) {
        const int R0c = blockIdx.x * 512 + t * 64 + w * 16;

        // ---- row absmax via LDS transpose (per-wave private buffer) ----
        #pragma unroll
        for (int r = 0; r < 16; ++r) {
            float4 v = xr[r];
            float m = fmaxf(fmaxf(fabsf(v.x), fabsf(v.y)),
                            fmaxf(fabsf(v.z), fabsf(v.w)));
            *(float*)(wbuf + r * 272 + l * 4) = m;
        }
        LGKM0(); SB();
        float mm;
        {
            const char* p = wbuf + lr * 272 + lg * 64;
            float4 a = *(const float4*)(p);
            float4 b = *(const float4*)(p + 16);
            float4 c = *(const float4*)(p + 32);
            float4 d = *(const float4*)(p + 48);
            float m0 = fmaxf(fmaxf(a.x, a.y), fmaxf(a.z, a.w));
            float m1 = fmaxf(fmaxf(b.x, b.y), fmaxf(b.z, b.w));
            float m2 = fmaxf(fmaxf(c.x, c.y), fmaxf(c.z, c.w));
            float m3 = fmaxf(fmaxf(d.x, d.y), fmaxf(d.z, d.w));
            mm = fmaxf(fmaxf(m0, m1), fmaxf(m2, m3));
        }
        mm = fmaxf(mm, __shfl_xor(mm, 16, 64));
        mm = fmaxf(mm, __shfl_xor(mm, 32, 64));     // lanes of row lr agree
        const float sA = QBF / fmaxf(mm, EPSF);
        const float rinv1 = 1.0f / (sA * ws1);

        // ---- quantize x -> i8 rows [16][256B @272 stride] ----
        #pragma unroll
        for (int r = 0; r < 16; ++r) {
            float s_r = bcast_lane(sA, r);
            float4 v = xr[r];
            *(u32*)(wbuf + r * 272 + l * 4) = packi8(v.x, v.y, v.z, v.w, s_r);
        }

        // ---- prefetch next tile's x (register reuse; overlaps compute) ----
        if (t + 1 < TPB) {
            const float* srcp = half ? evid : prior;
            int R0n = R0c + 64;
            #pragma unroll
            for (int r = 0; r < 16; ++r)
                xr[r] = *(const float4*)(srcp + (size_t)(R0n + r) * FF + lc * 4);
        }
        LGKM0(); SB();

        // ---- layer 1: i8 MFMA, K=256 (4 x 64), weights from LDS ----
        i32x4 acc1[8] = {};
        #pragma unroll
        for (int kb = 0; kb < 4; ++kb) {
            i32x4 xb = *(const i32x4*)(wbuf + lr * 272 + kb * 64 + lg * 16);
            #pragma unroll
            for (int ct = 0; ct < 8; ++ct) {
                i32x4 wa = *(const i32x4*)(smem + (ct * 4 + kb) * 1024 + l * 16);
                acc1[ct] = __builtin_amdgcn_mfma_i32_16x16x64_i8(wa, xb, acc1[ct], 0, 0, 0);
            }
        }

        // ---- epilogue 1: exact scale + bias + relu, lane-local requant ----
        float h[8][4];
        float hmax = 0.f;
        #pragma unroll
        for (int ct = 0; ct < 8; ++ct) {
            float4 b4 = *(const float4*)(bias1 + ct * 16 + lg * 4);
            h[ct][0] = fmaxf((float)acc1[ct][0] * rinv1 + b4.x, 0.f);
            h[ct][1] = fmaxf((float)acc1[ct][1] * rinv1 + b4.y, 0.f);
            h[ct][2] = fmaxf((float)acc1[ct][2] * rinv1 + b4.z, 0.f);
            h[ct][3] = fmaxf((float)acc1[ct][3] * rinv1 + b4.w, 0.f);
            hmax = fmaxf(hmax, fmaxf(fmaxf(h[ct][0], h[ct][1]),
                                     fmaxf(h[ct][2], h[ct][3])));
        }
        hmax = fmaxf(hmax, __shfl_xor(hmax, 16, 64));
        hmax = fmaxf(hmax, __shfl_xor(hmax, 32, 64));
        const float s2 = QBF / fmaxf(hmax, EPSF);
        const float rinv2 = 1.0f / (s2 * ws2);

        // ---- hq -> LDS rows (natural col order; reuses xq bytes, WAR-safe) ----
        #pragma unroll
        for (int ct = 0; ct < 8; ++ct)
            *(u32*)(wbuf + lr * 272 + ct * 16 + lg * 4) =
                packi8(h[ct][0], h[ct][1], h[ct][2], h[ct][3], s2);
        LGKM0(); SB();

        // ---- layer 2: i8 MFMA, K=128 (2 x 64) ----
        i32x4 acc2[8] = {};
        #pragma unroll
        for (int kb = 0; kb < 2; ++kb) {
            i32x4 hb = *(const i32x4*)(wbuf + lr * 272 + kb * 64 + lg * 16);
            #pragma unroll
            for (int ct = 0; ct < 8; ++ct) {
                i32x4 wa = *(const i32x4*)(smem + W2_OFF + (ct * 2 + kb) * 1024 + l * 16);
                acc2[ct] = __builtin_amdgcn_mfma_i32_16x16x64_i8(wa, hb, acc2[ct], 0, 0, 0);
            }
        }

        // ---- epilogue 2: sigmoid, * prior (L1-hot), 64B-segment stores ----
        const size_t rowoff = (size_t)(R0c + lr) * FF;
        #pragma unroll
        for (int ct = 0; ct < 8; ++ct) {
            float4 b4 = *(const float4*)(bias2 + ct * 16 + lg * 4);
            float4 pv = *(const float4*)(prior + rowoff + ct * 16 + lg * 4);
            float4 un;
            float y0 = (float)acc2[ct][0] * rinv2 + b4.x;
            float y1 = (float)acc2[ct][1] * rinv2 + b4.y;
            float y2 = (float)acc2[ct][2] * rinv2 + b4.z;
            float y3 = (float)acc2[ct][3] * rinv2 + b4.w;
            un.x = pv.x / (1.0f + __expf(-y0));
            un.y = pv.y / (1.0f + __expf(-y1));
            un.z = pv.z / (1.0f + __expf(-y2));
            un.w = pv.w / (1.0f + __expf(-y3));
            *(float4*)(out + rowoff + ct * 16 + lg * 4) = un;
            csum[ct][0] += un.x; csum[ct][1] += un.y;
            csum[ct][2] += un.z; csum[ct][3] += un.w;
        }
    }

    // ---- column sums: reduce over the 16 lr-lanes, once per block ----
    #pragma unroll
    for (int msk = 1; msk < 16; msk <<= 1) {
        #pragma unroll
        for (int ct = 0; ct < 8; ++ct) {
            #pragma unroll
            for (int j = 0; j < 4; ++j)
                csum[ct][j] += __shfl_xor(csum[ct][j], msk, 64);
        }
    }
    if (lr == 0) {
        #pragma unroll
        for (int ct = 0; ct < 8; ++ct) {
            float4 cv;
            cv.x = csum[ct][0]; cv.y = csum[ct][1];
            cv.z = csum[ct][2]; cv.w = csum[ct][3];
            *(float4*)(colsum + w * 128 + ct * 16 + lg * 4) = cv;
        }
    }
    __syncthreads();
    if (tid < FF)
        partials[(size_t)blockIdx.x * FF + tid] =
            colsum[tid] + colsum[128 + tid] + colsum[256 + tid] + colsum[384 + tid];
}

// ---------- kernel 4: deterministic normalizer (batch b <- blocks b*64..+64) ----
__global__ void norm_kernel(const float* __restrict__ partials, float* __restrict__ norm) {
    __shared__ float red[2][128];
    int b = blockIdx.x;                                // 8 blocks x 256 thr
    int f = threadIdx.x & 127, tg = threadIdx.x >> 7;
    float s = 0.f;
    for (int t = tg * 32; t < tg * 32 + 32; ++t)
        s += partials[((size_t)b * 64 + t) * FF + f];
    red[tg][f] = s; __syncthreads();
    if (tg == 0)
        norm[b * FF + f] = fmaxf(red[0][f] + red[1][f], 1e-10f);
}

// ---------- kernel 5: out /= norm ----------
__global__ void div_kernel(float* __restrict__ out, const float* __restrict__ norm) {
    size_t i4 = (size_t)blockIdx.x * blockDim.x + threadIdx.x;
    const size_t total4 = (size_t)NROWS * FF / 4;
    for (; i4 < total4; i4 += (size_t)gridDim.x * blockDim.x) {
        size_t i = i4 * 4;
        float4 v = *(float4*)(out + i);
        int b = (int)(i >> 22);                  // S*F = 2^22
        int f = (int)(i & 127);
        float4 nv = *(const float4*)(norm + b * FF + f);
        v.x /= nv.x; v.y /= nv.y; v.z /= nv.z; v.w /= nv.w;
        *(float4*)(out + i) = v;
    }
}

extern "C" void kernel_launch(void* const* d_in, const int* in_sizes, int n_in,
                              void* d_out, int out_size, void* d_ws, size_t ws_size,
                              hipStream_t stream) {
    const float* evid  = (const float*)d_in[0];
    const float* prior = (const float*)d_in[1];
    const float* W1    = (const float*)d_in[2];
    const float* b1    = (const float*)d_in[3];
    const float* W2    = (const float*)d_in[4];
    const float* b2    = (const float*)d_in[5];
    float* out = (float*)d_out;

    char* ws = (char*)d_ws;
    float*  hdr      = (float*)ws;                       // 64 B
    double* psum     = (double*)(ws + 256);              // 384 B
    char*   wq       = ws + 1024;                        // 48 KB (w1|w2 granules)
    float*  partials = (float*)(ws + 65536);             // 512*128*4 = 256 KB
    float*  norm     = (float*)(ws + 65536 + 262144);    // 4 KB

    pstats_kernel<<<48, 256, 0, stream>>>(W1, W2, psum);
    sfinal_kernel<<<1, 64, 0, stream>>>(psum, hdr);
    wquant_kernel<<<12, 256, 0, stream>>>(W1, W2, hdr, wq);
    fused_kernel<<<NBLK, 256, 0, stream>>>(evid, prior, b1, b2, wq, hdr, out, partials);
    norm_kernel<<<8, 256, 0, stream>>>(partials, norm);
    div_kernel<<<2048, 256, 0, stream>>>(out, norm);
}